// Round 9
// baseline (481.722 us; speedup 1.0000x reference)
//
#include <hip/hip_runtime.h>
#include <hip/hip_bf16.h>

#define NN 500000
#define NE 8000000
#define NB 123           // buckets of 4096 nodes: 123*4096 = 503808 >= NN
#define BSH 12
#define BSZ 4096
#define CAP 69632        // fixed bucket capacity (65536 mean + 16 sigma), mult of 4
#define M 8              // slices (blocks) per bucket
#define NAGG (NB * M)    // 984 blocks
#define BN_EPS 1e-5f
#define M19 524287u

typedef unsigned uv4 __attribute__((ext_vector_type(4)));
typedef int iv4 __attribute__((ext_vector_type(4)));
typedef float fv4 __attribute__((ext_vector_type(4)));
typedef unsigned long long u64;

__device__ __forceinline__ float waveReduceF(float v) {
#pragma unroll
    for (int o = 32; o > 0; o >>= 1) v += __shfl_down(v, o, 64);
    return v;
}
__device__ __forceinline__ double waveReduceD(double v) {
#pragma unroll
    for (int o = 32; o > 0; o >>= 1) v += __shfl_down(v, o, 64);
    return v;
}
__device__ __forceinline__ float u2f(unsigned short u) {
    return __bfloat162float(__builtin_bit_cast(__hip_bfloat16, u));
}
__device__ __forceinline__ unsigned short f2u(float f) {
    return __builtin_bit_cast(unsigned short, __float2bfloat16(f));
}
// pack x-sample into (fixed<<20)+count1.  |x|<6 -> x*2^28 < 2^31 (int ok)
__device__ __forceinline__ u64 pk1(float v) {
    int iv = (int)rintf(v * 268435456.f);              // 2^28
    return ((u64)(long long)iv << 20) + 1ull;
}

// ---------------- bucketize: block counting sort, packed LDS record ------------
__global__ __launch_bounds__(512) void scatterk(
    const iv4* __restrict__ src4, const iv4* __restrict__ dst4,
    const fv4* __restrict__ w4, int* __restrict__ cur,
    unsigned* __restrict__ pairs, unsigned short* __restrict__ wp)
{
    __shared__ u64 sPack[4096];    // 32 KB: [en:32][w:16][b:16]
    __shared__ int h[128];         // block-wide histogram
    __shared__ int bOff[128];      // block-local bucket prefix
    __shared__ int lb[128];        // global base for this block per bucket

    int tid = threadIdx.x;
    for (int j = tid; j < 128; j += 512) h[j] = 0;
    __syncthreads();

    unsigned en[8]; unsigned short wb[8]; int rb[8];   // rk<<8 | b, or -1
#pragma unroll
    for (int k = 0; k < 2; k++) {
        int q = blockIdx.x * 1024 + k * 512 + tid;
        if (q < NE / 4) {
            iv4 s4 = __builtin_nontemporal_load(src4 + q);
            iv4 d4 = __builtin_nontemporal_load(dst4 + q);
            fv4 ww = __builtin_nontemporal_load(w4 + q);
            int ss[4] = {s4.x, s4.y, s4.z, s4.w};
            int dd[4] = {d4.x, d4.y, d4.z, d4.w};
            float fw[4] = {ww.x, ww.y, ww.z, ww.w};
#pragma unroll
            for (int i = 0; i < 4; i++) {
                int d = dd[i], b = d >> BSH;
                en[k * 4 + i] = ((unsigned)(d & (BSZ - 1)) << 19) | (unsigned)ss[i];
                wb[k * 4 + i] = f2u(fw[i]);
                int rk = atomicAdd(&h[b], 1);
                rb[k * 4 + i] = (rk << 8) | b;
            }
        } else {
#pragma unroll
            for (int i = 0; i < 4; i++) rb[k * 4 + i] = -1;
        }
    }
    __syncthreads();
    if (tid < NB) lb[tid] = tid * CAP + atomicAdd(&cur[tid], h[tid]);
    // wave-parallel exclusive prefix of h -> bOff (lanes 0..63, 2 elems each)
    if (tid < 64) {
        int lane = tid;
        int a = (2 * lane < NB) ? h[2 * lane] : 0;
        int b = (2 * lane + 1 < NB) ? h[2 * lane + 1] : 0;
        int s = a + b;
#pragma unroll
        for (int o = 1; o < 64; o <<= 1) {
            int t = __shfl_up(s, o, 64);
            if (lane >= o) s += t;
        }
        int excl = s - (a + b);
        bOff[2 * lane] = excl;
        bOff[2 * lane + 1] = excl + a;
    }
    __syncthreads();
#pragma unroll
    for (int k = 0; k < 8; k++) {
        if (rb[k] >= 0) {
            int b = rb[k] & 255, rk = rb[k] >> 8;
            int pos = bOff[b] + rk;
            sPack[pos] = ((u64)en[k] << 32) | ((u64)wb[k] << 16) | (unsigned)b;
        }
    }
    __syncthreads();
    int nE = NE - blockIdx.x * 4096; if (nE > 4096) nE = 4096;
    for (int j = tid; j < nE; j += 512) {
        u64 v = sPack[j];
        int b = (int)(v & 0xFF);
        int glob = lb[b] + (j - bOff[b]);
        __builtin_nontemporal_store((unsigned)(v >> 32), pairs + glob);
        __builtin_nontemporal_store((unsigned short)(v >> 16), wp + glob);
    }
}

// ---------------- agg pass 1: packed u64 atomics, 3-deep rotation --------------
__global__ __launch_bounds__(512) void agg1k(
    const unsigned* __restrict__ pairs, const int* __restrict__ cur,
    const float* __restrict__ x, u64* __restrict__ slab)
{
    __shared__ u64 t[BSZ];   // 32 KB
    for (int j = threadIdx.x; j < BSZ; j += 512) t[j] = 0ull;
    __syncthreads();
    int B = blockIdx.x / M, sl = blockIdx.x % M;
    int b0 = B * CAP;
    int len = cur[B];
    int seg = (((len + M - 1) / M) + 3) & ~3;
    int lo = b0 + sl * seg;
    int hi = lo + seg, e1 = b0 + len;
    if (hi > e1) hi = e1;
    int n = hi - lo;
    if (n > 0) {
        int nq = n >> 2;
        const uv4* pq = (const uv4*)(pairs + lo);
        int i1 = threadIdx.x;
        uv4 pA; float a0, a1, a2, a3; bool vA = i1 < nq;
        if (vA) {
            pA = __builtin_nontemporal_load(pq + i1);
            a0 = x[pA.x & M19]; a1 = x[pA.y & M19];
            a2 = x[pA.z & M19]; a3 = x[pA.w & M19];
        }
        int i2 = i1 + 512;
        uv4 pB; float b0v, b1v, b2v, b3v; bool vB = i2 < nq;
        if (vB) {
            pB = __builtin_nontemporal_load(pq + i2);
            b0v = x[pB.x & M19]; b1v = x[pB.y & M19];
            b2v = x[pB.z & M19]; b3v = x[pB.w & M19];
        }
        int i3 = i2 + 512;
        uv4 pC; float c0, c1, c2, c3; bool vC = i3 < nq;
        if (vC) {
            pC = __builtin_nontemporal_load(pq + i3);
            c0 = x[pC.x & M19]; c1 = x[pC.y & M19];
            c2 = x[pC.z & M19]; c3 = x[pC.w & M19];
        }
        int inx = i3 + 512;
        while (vA) {
            uv4 pD; float d0, d1, d2, d3; bool vD = inx < nq;
            if (vD) {
                pD = __builtin_nontemporal_load(pq + inx);
                d0 = x[pD.x & M19]; d1 = x[pD.y & M19];
                d2 = x[pD.z & M19]; d3 = x[pD.w & M19];
            }
            atomicAdd(&t[pA.x >> 19], pk1(a0));
            atomicAdd(&t[pA.y >> 19], pk1(a1));
            atomicAdd(&t[pA.z >> 19], pk1(a2));
            atomicAdd(&t[pA.w >> 19], pk1(a3));
            pA = pB; a0 = b0v; a1 = b1v; a2 = b2v; a3 = b3v; vA = vB;
            pB = pC; b0v = c0; b1v = c1; b2v = c2; b3v = c3; vB = vC;
            pC = pD; c0 = d0; c1 = d1; c2 = d2; c3 = d3; vC = vD;
            inx += 512;
        }
        int rem = n & 3;
        if ((int)threadIdx.x < rem) {
            unsigned p = pairs[lo + (nq << 2) + threadIdx.x];
            atomicAdd(&t[p >> 19], pk1(x[p & M19]));
        }
    }
    __syncthreads();
    u64* sb = slab + (size_t)blockIdx.x * BSZ;
    for (int j = threadIdx.x; j < BSZ; j += 512)
        __builtin_nontemporal_store(t[j], sb + j);
}

// decode: count in low 20 bits, x-sum (2^-28 fixed) above.  Also emit the
// pre-packed agg2 operand ENC = (u*2^26)<<22 + n  (one 8B gather, one u64 atomic)
__global__ __launch_bounds__(256) void mergeN1(
    const u64* __restrict__ slab, const float* __restrict__ x,
    float2* __restrict__ UN2, u64* __restrict__ ENC)
{
    int i = blockIdx.x * 256 + threadIdx.x;
    if (i >= NN) return;
    int B = i >> BSH, low = i & (BSZ - 1);
    u64 s = 0ull;
#pragma unroll
    for (int m = 0; m < M; m++)
        s += __builtin_nontemporal_load(slab + (size_t)(B * M + m) * BSZ + low);
    unsigned cn = (unsigned)(s & 0xFFFFFull);
    long long sv = (long long)(s - (u64)cn) >> 20;
    float u = x[i] + (float)((double)sv * 3.725290298461914e-09);  // 2^-28
    UN2[i] = make_float2(u, (float)cn);
    long long iu = (long long)rintf(u * 67108864.f);               // 2^26
    ENC[i] = ((u64)iu << 22) + (u64)cn;
}

// ---------------- agg pass 2: gather pre-packed ENC, 3-deep rotation -----------
__global__ __launch_bounds__(512) void agg2k(
    const unsigned* __restrict__ pairs, const int* __restrict__ cur,
    const u64* __restrict__ ENC, u64* __restrict__ slab)
{
    __shared__ u64 t[BSZ];   // 32 KB
    for (int j = threadIdx.x; j < BSZ; j += 512) t[j] = 0ull;
    __syncthreads();
    int B = blockIdx.x / M, sl = blockIdx.x % M;
    int b0 = B * CAP;
    int len = cur[B];
    int seg = (((len + M - 1) / M) + 3) & ~3;
    int lo = b0 + sl * seg;
    int hi = lo + seg, e1 = b0 + len;
    if (hi > e1) hi = e1;
    int n = hi - lo;
    if (n > 0) {
        int nq = n >> 2;
        const uv4* pq = (const uv4*)(pairs + lo);
        int i1 = threadIdx.x;
        uv4 pA; u64 a0, a1, a2, a3; bool vA = i1 < nq;
        if (vA) {
            pA = __builtin_nontemporal_load(pq + i1);
            a0 = ENC[pA.x & M19]; a1 = ENC[pA.y & M19];
            a2 = ENC[pA.z & M19]; a3 = ENC[pA.w & M19];
        }
        int i2 = i1 + 512;
        uv4 pB; u64 b0v, b1v, b2v, b3v; bool vB = i2 < nq;
        if (vB) {
            pB = __builtin_nontemporal_load(pq + i2);
            b0v = ENC[pB.x & M19]; b1v = ENC[pB.y & M19];
            b2v = ENC[pB.z & M19]; b3v = ENC[pB.w & M19];
        }
        int i3 = i2 + 512;
        uv4 pC; u64 c0, c1, c2, c3; bool vC = i3 < nq;
        if (vC) {
            pC = __builtin_nontemporal_load(pq + i3);
            c0 = ENC[pC.x & M19]; c1 = ENC[pC.y & M19];
            c2 = ENC[pC.z & M19]; c3 = ENC[pC.w & M19];
        }
        int inx = i3 + 512;
        while (vA) {
            uv4 pD; u64 d0, d1, d2, d3; bool vD = inx < nq;
            if (vD) {
                pD = __builtin_nontemporal_load(pq + inx);
                d0 = ENC[pD.x & M19]; d1 = ENC[pD.y & M19];
                d2 = ENC[pD.z & M19]; d3 = ENC[pD.w & M19];
            }
            atomicAdd(&t[pA.x >> 19], a0);
            atomicAdd(&t[pA.y >> 19], a1);
            atomicAdd(&t[pA.z >> 19], a2);
            atomicAdd(&t[pA.w >> 19], a3);
            pA = pB; a0 = b0v; a1 = b1v; a2 = b2v; a3 = b3v; vA = vB;
            pB = pC; b0v = c0; b1v = c1; b2v = c2; b3v = c3; vB = vC;
            pC = pD; c0 = d0; c1 = d1; c2 = d2; c3 = d3; vC = vD;
            inx += 512;
        }
        int rem = n & 3;
        if ((int)threadIdx.x < rem) {
            unsigned p = pairs[lo + (nq << 2) + threadIdx.x];
            atomicAdd(&t[p >> 19], ENC[p & M19]);
        }
    }
    __syncthreads();
    u64* sb = slab + (size_t)blockIdx.x * BSZ;
    for (int j = threadIdx.x; j < BSZ; j += 512)
        __builtin_nontemporal_store(t[j], sb + j);
}

__global__ __launch_bounds__(256) void mergeN2(
    const u64* __restrict__ slab, float* __restrict__ SU, float* __restrict__ SN)
{
    int i = blockIdx.x * 256 + threadIdx.x;
    if (i >= NN) return;
    int B = i >> BSH, low = i & (BSZ - 1);
    u64 s = 0ull;
#pragma unroll
    for (int m = 0; m < M; m++)
        s += __builtin_nontemporal_load(slab + (size_t)(B * M + m) * BSZ + low);
    unsigned sn = (unsigned)(s & 0x3FFFFFull);
    long long sv = (long long)(s - (u64)sn) >> 22;
    float su = (float)((double)sv * 1.4901161193847656e-08);   // 2^-26
    SU[i] = su;
    SN[i] = (float)sn;
}

// ---------------- agg pass 3: 4B gather from SU, 3-deep rotation ---------------
__global__ __launch_bounds__(512) void agg3k(
    const unsigned* __restrict__ pairs, const int* __restrict__ cur,
    const float* __restrict__ SU, float* __restrict__ slab)
{
    __shared__ float t[BSZ];   // 16 KB
    for (int j = threadIdx.x; j < BSZ; j += 512) t[j] = 0.f;
    __syncthreads();
    int B = blockIdx.x / M, sl = blockIdx.x % M;
    int b0 = B * CAP;
    int len = cur[B];
    int seg = (((len + M - 1) / M) + 3) & ~3;
    int lo = b0 + sl * seg;
    int hi = lo + seg, e1 = b0 + len;
    if (hi > e1) hi = e1;
    int n = hi - lo;
    if (n > 0) {
        int nq = n >> 2;
        const uv4* pq = (const uv4*)(pairs + lo);
        int i1 = threadIdx.x;
        uv4 pA; float a0, a1, a2, a3; bool vA = i1 < nq;
        if (vA) {
            pA = __builtin_nontemporal_load(pq + i1);
            a0 = SU[pA.x & M19]; a1 = SU[pA.y & M19];
            a2 = SU[pA.z & M19]; a3 = SU[pA.w & M19];
        }
        int i2 = i1 + 512;
        uv4 pB; float b0v, b1v, b2v, b3v; bool vB = i2 < nq;
        if (vB) {
            pB = __builtin_nontemporal_load(pq + i2);
            b0v = SU[pB.x & M19]; b1v = SU[pB.y & M19];
            b2v = SU[pB.z & M19]; b3v = SU[pB.w & M19];
        }
        int i3 = i2 + 512;
        uv4 pC; float c0, c1, c2, c3; bool vC = i3 < nq;
        if (vC) {
            pC = __builtin_nontemporal_load(pq + i3);
            c0 = SU[pC.x & M19]; c1 = SU[pC.y & M19];
            c2 = SU[pC.z & M19]; c3 = SU[pC.w & M19];
        }
        int inx = i3 + 512;
        while (vA) {
            uv4 pD; float d0, d1, d2, d3; bool vD = inx < nq;
            if (vD) {
                pD = __builtin_nontemporal_load(pq + inx);
                d0 = SU[pD.x & M19]; d1 = SU[pD.y & M19];
                d2 = SU[pD.z & M19]; d3 = SU[pD.w & M19];
            }
            atomicAdd(&t[pA.x >> 19], a0);
            atomicAdd(&t[pA.y >> 19], a1);
            atomicAdd(&t[pA.z >> 19], a2);
            atomicAdd(&t[pA.w >> 19], a3);
            pA = pB; a0 = b0v; a1 = b1v; a2 = b2v; a3 = b3v; vA = vB;
            pB = pC; b0v = c0; b1v = c1; b2v = c2; b3v = c3; vB = vC;
            pC = pD; c0 = d0; c1 = d1; c2 = d2; c3 = d3; vC = vD;
            inx += 512;
        }
        int rem = n & 3;
        if ((int)threadIdx.x < rem) {
            unsigned p = pairs[lo + (nq << 2) + threadIdx.x];
            atomicAdd(&t[p >> 19], SU[p & M19]);
        }
    }
    __syncthreads();
    float* sb = slab + (size_t)blockIdx.x * BSZ;
    for (int j = threadIdx.x; j < BSZ; j += 512)
        __builtin_nontemporal_store(t[j], sb + j);
}

// ---------------- fused: merge SSU + f64 moments of (u,n,su,sn,ssu) ------------
__global__ __launch_bounds__(256) void m3mom(
    const float* __restrict__ slab, const float2* __restrict__ UN2,
    const float* __restrict__ SU, const float* __restrict__ SN,
    float* __restrict__ SSU, double* __restrict__ dm)
{
    int i = blockIdx.x * 256 + threadIdx.x;
    double z[5] = {0, 0, 0, 0, 0};
    if (i < NN) {
        int B = i >> BSH, low = i & (BSZ - 1);
        float ssu = 0.f;
#pragma unroll
        for (int m = 0; m < M; m++)
            ssu += __builtin_nontemporal_load(slab + (size_t)(B * M + m) * BSZ + low);
        SSU[i] = ssu;
        float2 un = UN2[i];
        z[0] = (double)un.x; z[1] = (double)un.y; z[2] = (double)SU[i];
        z[3] = (double)SN[i]; z[4] = (double)ssu;
    }
    double m[20];
#pragma unroll
    for (int a = 0; a < 5; a++) m[a] = z[a];
    int idx = 5;
#pragma unroll
    for (int a = 0; a < 5; a++)
#pragma unroll
        for (int b = a; b < 5; b++) m[idx++] = z[a] * z[b];

    __shared__ double part[4][20];
    int lane = threadIdx.x & 63, wid = threadIdx.x >> 6;
#pragma unroll
    for (int k = 0; k < 20; k++) {
        double r = waveReduceD(m[k]);
        if (lane == 0) part[wid][k] = r;
    }
    __syncthreads();
    if (threadIdx.x < 20)
        atomicAdd(&dm[threadIdx.x],
                  part[0][threadIdx.x] + part[1][threadIdx.x] +
                  part[2][threadIdx.x] + part[3][threadIdx.x]);
}

// ---------------- K: wave-parallel fold of weights + moments -> 4x6 logits -----
__global__ __launch_bounds__(64) void constk(
    const float* __restrict__ W1a, const float* __restrict__ b1a,
    const float* __restrict__ W1b, const float* __restrict__ b1b,
    const float* __restrict__ g1, const float* __restrict__ be1,
    const float* __restrict__ W2a, const float* __restrict__ b2a,
    const float* __restrict__ W2b, const float* __restrict__ b2b,
    const float* __restrict__ g2, const float* __restrict__ be2,
    const float* __restrict__ W3a, const float* __restrict__ b3a,
    const float* __restrict__ W3b, const float* __restrict__ b3b,
    const float* __restrict__ g3, const float* __restrict__ be3,
    const float* __restrict__ Wf, const float* __restrict__ bf_,
    const double* __restrict__ dm, float* __restrict__ Lout)
{
    __shared__ float sw[768];
    __shared__ double sdm[20];
    __shared__ float vv[9][10];   // p,q,rt,st,dt,rh,sh,th,dh
    int t = threadIdx.x;
    if (t < 10) {
        sw[0 + t] = W1a[t];  sw[10 + t] = b1a[t];  sw[120 + t] = b1b[t];
        sw[130 + t] = g1[t]; sw[140 + t] = be1[t];
        sw[250 + t] = b2a[t]; sw[360 + t] = b2b[t];
        sw[370 + t] = g2[t]; sw[380 + t] = be2[t];
        sw[490 + t] = b3a[t]; sw[600 + t] = b3b[t];
        sw[610 + t] = g3[t]; sw[620 + t] = be3[t];
    }
    for (int i = t; i < 100; i += 64) {
        sw[20 + i]  = W1b[i];
        sw[150 + i] = W2a[i];
        sw[260 + i] = W2b[i];
        sw[390 + i] = W3a[i];
        sw[500 + i] = W3b[i];
    }
    for (int i = t; i < 120; i += 64) sw[630 + i] = Wf[i];
    if (t < 4)  sw[750 + t] = bf_[t];
    if (t < 20) sdm[t] = dm[t];
    __syncthreads();

    const double invN = 1.0 / (double)NN;
    double E[5];
#pragma unroll
    for (int m = 0; m < 5; m++) E[m] = sdm[m] * invN;
    double C[5][5];
    {
        int idx = 5;
#pragma unroll
        for (int a = 0; a < 5; a++)
#pragma unroll
            for (int b = a; b < 5; b++) {
                double c = sdm[idx++] * invN - E[a] * E[b];
                C[a][b] = c; C[b][a] = c;
            }
    }
    int j = t;   // lane j owns output column j (j<10)
    if (j < 10) {
        float vj = 0.f;
        for (int k = 0; k < 10; k++) vj += sw[0 + k] * sw[20 + k * 10 + j];
        float var1 = (float)(C[0][0] * (double)vj * (double)vj);
        float sc1 = sw[130 + j] * rsqrtf(var1 + BN_EPS);
        float pj = sc1 * vj;
        float qj = sw[140 + j] - (float)E[0] * pj;
        vv[0][j] = pj; vv[1][j] = qj;
    }
    __syncthreads();
    if (j < 10) {
        float tp[10], tq[10];
        for (int m = 0; m < 10; m++) {
            float ap = 0.f, aq = 0.f;
            for (int k = 0; k < 10; k++) {
                float w = sw[150 + k * 10 + m];
                ap += vv[0][k] * w; aq += vv[1][k] * w;
            }
            tp[m] = ap; tq[m] = aq;
        }
        float rj = 0.f, sj = 0.f;
        for (int m = 0; m < 10; m++) {
            float w = sw[260 + m * 10 + j];
            rj += tp[m] * w; sj += tq[m] * w;
        }
        double Ea = E[0] + E[2], Eb = 1.0 + E[1];
        double Va = C[0][0] + 2.0 * C[0][2] + C[2][2];
        double Vb = C[1][1];
        double Cab = C[0][1] + C[2][1];
        double rjd = rj, sjd = sj;
        float var2 = (float)(Va * rjd * rjd + Vb * sjd * sjd + 2.0 * Cab * rjd * sjd);
        float sc2 = sw[370 + j] * rsqrtf(var2 + BN_EPS);
        vv[2][j] = sc2 * rj;
        vv[3][j] = sc2 * sj;
        vv[4][j] = sw[380 + j] - sc2 * (float)(Ea * rjd + Eb * sjd);
    }
    __syncthreads();
    if (j < 10) {
        float tr[10], ts[10], tt[10];
        for (int m = 0; m < 10; m++) {
            float ar = 0.f, as = 0.f, at = 0.f;
            for (int k = 0; k < 10; k++) {
                float w = sw[390 + k * 10 + m];
                ar += vv[2][k] * w; as += vv[3][k] * w; at += vv[4][k] * w;
            }
            tr[m] = ar; ts[m] = as; tt[m] = at;
        }
        float r3 = 0.f, s3 = 0.f, t3 = 0.f;
        for (int m = 0; m < 10; m++) {
            float w = sw[500 + m * 10 + j];
            r3 += tr[m] * w; s3 += ts[m] * w; t3 += tt[m] * w;
        }
        const double gA[5] = {1, 0, 2, 0, 1};
        const double gB[5] = {0, 2, 0, 1, 0};
        const double gC[5] = {0, 1, 0, 0, 0};
        double EA = E[0] + 2.0 * E[2] + E[4];
        double EB = 1.0 + 2.0 * E[1] + E[3];
        double EC = 1.0 + E[1];
        double VA = 0, VB = 0, VC = 0, CAB = 0, CAC = 0, CBC = 0;
        for (int a = 0; a < 5; a++)
            for (int b = 0; b < 5; b++) {
                double c = C[a][b];
                VA  += gA[a] * gA[b] * c;
                VB  += gB[a] * gB[b] * c;
                VC  += gC[a] * gC[b] * c;
                CAB += gA[a] * gB[b] * c;
                CAC += gA[a] * gC[b] * c;
                CBC += gB[a] * gC[b] * c;
            }
        double r3d = r3, s3d = s3, t3d = t3;
        float var3 = (float)(VA * r3d * r3d + VB * s3d * s3d + VC * t3d * t3d
                             + 2.0 * (CAB * r3d * s3d + CAC * r3d * t3d + CBC * s3d * t3d));
        float sc3 = sw[610 + j] * rsqrtf(var3 + BN_EPS);
        vv[5][j] = sc3 * r3;
        vv[6][j] = sc3 * s3;
        vv[7][j] = sc3 * t3;
        vv[8][j] = sw[620 + j] - sc3 * (float)(EA * r3d + EB * s3d + EC * t3d);
    }
    __syncthreads();
    if (t < 4) {
        int k = t;
        float Lu = 0, Ln = 0, Lsu = 0, Lsn = 0, Lssu = 0, L0 = sw[750 + k];
        for (int j2 = 0; j2 < 10; j2++) {
            float wf1 = sw[630 + j2 * 4 + k];
            float wf2 = sw[630 + (10 + j2) * 4 + k];
            float wf3 = sw[630 + (20 + j2) * 4 + k];
            Lu   += vv[0][j2] * wf1 + vv[2][j2] * wf2 + vv[5][j2] * wf3;
            Ln   += vv[3][j2] * wf2 + (2.f * vv[6][j2] + vv[7][j2]) * wf3;
            Lsu  += vv[2][j2] * wf2 + 2.f * vv[5][j2] * wf3;
            Lsn  += vv[6][j2] * wf3;
            Lssu += vv[5][j2] * wf3;
            L0   += vv[1][j2] * wf1 + (vv[3][j2] + vv[4][j2]) * wf2
                  + (vv[6][j2] + vv[7][j2] + vv[8][j2]) * wf3;
        }
        Lout[0 * 4 + k] = Lu;  Lout[1 * 4 + k] = Ln;   Lout[2 * 4 + k] = Lsu;
        Lout[3 * 4 + k] = Lsn; Lout[4 * 4 + k] = Lssu; Lout[5 * 4 + k] = L0;
    }
}

// ---------------- F: logits -> softmax -> s (f32 out + bf16 side table) --------
__global__ __launch_bounds__(256) void finalk(
    const float2* __restrict__ UN2, const float* __restrict__ SU,
    const float* __restrict__ SN, const float* __restrict__ SSU,
    const float* __restrict__ L,
    float4* __restrict__ sout, ushort4* __restrict__ sbf)
{
    __shared__ float sL[24];
    if (threadIdx.x < 24) sL[threadIdx.x] = L[threadIdx.x];
    __syncthreads();
    int i = blockIdx.x * 256 + threadIdx.x;
    if (i >= NN) return;
    float2 un = UN2[i];
    float u = un.x, n = un.y, su = SU[i], sn = SN[i], ssu = SSU[i];
    float lg[4];
#pragma unroll
    for (int k = 0; k < 4; k++)
        lg[k] = sL[k] * u + sL[4 + k] * n + sL[8 + k] * su
              + sL[12 + k] * sn + sL[16 + k] * ssu + sL[20 + k];
    float mx = fmaxf(fmaxf(lg[0], lg[1]), fmaxf(lg[2], lg[3]));
    float e0 = __expf(lg[0] - mx), e1 = __expf(lg[1] - mx);
    float e2 = __expf(lg[2] - mx), e3 = __expf(lg[3] - mx);
    float inv = 1.f / (e0 + e1 + e2 + e3);
    float s0 = e0 * inv, s1 = e1 * inv, s2 = e2 * inv, s3 = e3 * inv;
    fv4 o = {s0, s1, s2, s3};
    __builtin_nontemporal_store(o, (fv4*)sout + i);
    ushort4 pk; pk.x = f2u(s0); pk.y = f2u(s1); pk.z = f2u(s2); pk.w = f2u(s3);
    sbf[i] = pk;
}

// ---------------- modk: dst-side s in LDS, 2-deep rotation, NO fence -----------
__device__ __forceinline__ void modacc(u64 ua, u64 ub, float we, float* acc) {
    float ax = u2f((unsigned short)ua),         ay = u2f((unsigned short)(ua >> 16));
    float az = u2f((unsigned short)(ua >> 32)), aw = u2f((unsigned short)(ua >> 48));
    float bx = u2f((unsigned short)ub),         by = u2f((unsigned short)(ub >> 16));
    float bz = u2f((unsigned short)(ub >> 32)), bw = u2f((unsigned short)(ub >> 48));
    acc[0] += we;
    acc[1] += we * (ax * bx + ay * by + az * bz + aw * bw);
    acc[2] += we * ax; acc[3] += we * ay;
    acc[4] += we * az; acc[5] += we * aw;
}

__global__ __launch_bounds__(512) void modk(
    const unsigned* __restrict__ pairs, const unsigned short* __restrict__ wp,
    const int* __restrict__ cur, const u64* __restrict__ sbfU,
    float* __restrict__ scal)
{
    __shared__ u64 sS[BSZ];   // 32 KB: this bucket's dst-side s values
    int B = blockIdx.x / M, sl = blockIdx.x % M;
    for (int j = threadIdx.x; j < BSZ; j += 512) {
        int g = (B << BSH) + j;
        sS[j] = (g < NN) ? sbfU[g] : 0ull;
    }
    __syncthreads();
    int b0 = B * CAP;
    int len = cur[B];
    int seg = (((len + M - 1) / M) + 3) & ~3;
    int lo = b0 + sl * seg;
    int hi = lo + seg, e1 = b0 + len;
    if (hi > e1) hi = e1;
    int n = hi - lo;
    float acc[6] = {0, 0, 0, 0, 0, 0};
    if (n > 0) {
        int nq = n >> 2;
        const uv4* pq = (const uv4*)(pairs + lo);
        const u64* wq = (const u64*)(wp + lo);
        int i1 = threadIdx.x;
        uv4 pA; u64 wA, a0, a1, a2, a3; bool vA = i1 < nq;
        if (vA) {
            pA = __builtin_nontemporal_load(pq + i1);
            wA = __builtin_nontemporal_load(wq + i1);
            a0 = sbfU[pA.x & M19]; a1 = sbfU[pA.y & M19];
            a2 = sbfU[pA.z & M19]; a3 = sbfU[pA.w & M19];
        }
        int i2 = i1 + 512;
        while (vA) {
            uv4 pB; u64 wB, b0v, b1v, b2v, b3v; bool vB = i2 < nq;
            if (vB) {
                pB = __builtin_nontemporal_load(pq + i2);
                wB = __builtin_nontemporal_load(wq + i2);
                b0v = sbfU[pB.x & M19]; b1v = sbfU[pB.y & M19];
                b2v = sbfU[pB.z & M19]; b3v = sbfU[pB.w & M19];
            }
            modacc(a0, sS[pA.x >> 19], u2f((unsigned short)wA),         acc);
            modacc(a1, sS[pA.y >> 19], u2f((unsigned short)(wA >> 16)), acc);
            modacc(a2, sS[pA.z >> 19], u2f((unsigned short)(wA >> 32)), acc);
            modacc(a3, sS[pA.w >> 19], u2f((unsigned short)(wA >> 48)), acc);
            pA = pB; wA = wB;
            a0 = b0v; a1 = b1v; a2 = b2v; a3 = b3v;
            vA = vB; i2 += 512;
        }
        int rem = n & 3;
        if ((int)threadIdx.x < rem) {
            int idx = lo + (nq << 2) + threadIdx.x;
            unsigned p = pairs[idx];
            modacc(sbfU[p & M19], sS[p >> 19], u2f(wp[idx]), acc);
        }
    }
    __shared__ float part[8][6];
    int lane = threadIdx.x & 63, wid = threadIdx.x >> 6;
#pragma unroll
    for (int k = 0; k < 6; k++) {
        float r = waveReduceF(acc[k]);
        if (lane == 0) part[wid][k] = r;
    }
    __syncthreads();
    if (threadIdx.x < 6) {
        float vsum = 0.f;
#pragma unroll
        for (int wdi = 0; wdi < 8; wdi++) vsum += part[wdi][threadIdx.x];
        int off = (threadIdx.x == 0) ? 128 : (threadIdx.x == 1 ? 129 : 130 + threadIdx.x);
        atomicAdd(&scal[off], vsum);
    }
}

// ---------------- q ------------------------------------------------------------
__global__ void qk(const float* __restrict__ scal, float* __restrict__ out)
{
    if (threadIdx.x == 0) {
        float inv = 1.f / scal[128];
        float posv = scal[129] * inv;
        float acc = 0.f;
#pragma unroll
        for (int k = 0; k < 4; k++) {
            float d = scal[132 + k] * inv;
            acc += d * d;
        }
        out[(size_t)NN * 4] = posv - acc;
    }
}

extern "C" void kernel_launch(void* const* d_in, const int* in_sizes, int n_in,
                              void* d_out, int out_size, void* d_ws, size_t ws_size,
                              hipStream_t stream) {
    const float* x  = (const float*)d_in[0];
    const int*  ei  = (const int*)d_in[1];
    const int*  src = ei;
    const int*  dst = ei + NE;
    const float* w   = (const float*)d_in[2];
    const float* W1a = (const float*)d_in[3];  const float* b1a = (const float*)d_in[4];
    const float* W1b = (const float*)d_in[5];  const float* b1b = (const float*)d_in[6];
    const float* g1  = (const float*)d_in[7];  const float* be1 = (const float*)d_in[8];
    const float* W2a = (const float*)d_in[9];  const float* b2a = (const float*)d_in[10];
    const float* W2b = (const float*)d_in[11]; const float* b2b = (const float*)d_in[12];
    const float* g2  = (const float*)d_in[13]; const float* be2 = (const float*)d_in[14];
    const float* W3a = (const float*)d_in[15]; const float* b3a = (const float*)d_in[16];
    const float* W3b = (const float*)d_in[17]; const float* b3b = (const float*)d_in[18];
    const float* g3  = (const float*)d_in[19]; const float* be3 = (const float*)d_in[20];
    const float* Wf  = (const float*)d_in[21]; const float* bfb = (const float*)d_in[22];

    // workspace layout:
    //  floats sc[0..1023]: two_m@128, pos@129, ds@132..135, L@160..183,
    //    dm (20 doubles) @ float-idx 384 (byte 1536),
    //    cur ints @ sci[832..954]  (all inside the 4KB memset region)
    //  byte 4096: pairs uint[NB*CAP] (34.3MB) | wp ushort[NB*CAP] (17.1MB) |
    //    slab (32.25MB, u64[NAGG*BSZ] rounds 1/2, float[NAGG*BSZ] round 3) |
    //    UN2 float2[NN] | SU float[NN] | SN float[NN] | SSU float[NN] |
    //    sbf ushort4[NN] | ENC u64[NN]
    float*  sc   = (float*)d_ws;
    int*    sci  = (int*)d_ws;
    double* dm   = (double*)(sc + 384);
    unsigned* pairs = (unsigned*)(sc + 1024);
    unsigned short* wp = (unsigned short*)(pairs + (size_t)NB * CAP);
    float*  slab = (float*)(wp + (size_t)NB * CAP);
    u64*    slabU = (u64*)slab;
    float2* UN2  = (float2*)(slab + (size_t)NAGG * 2 * BSZ);
    float*  SU   = (float*)(UN2 + NN);
    float*  SN   = SU + NN;
    float*  SSU  = SN + NN;
    ushort4* sbf = (ushort4*)(SSU + NN);
    u64*    ENC  = (u64*)(sbf + NN);
    float*  sout = (float*)d_out;

    const int NB_N  = (NN + 255) / 256;
    const int NB_EQ = (NE / 4 + 1023) / 1024;   // 1954 blocks over int4-quads

    hipMemsetAsync(sc, 0, 4096, stream);

    // bucketize once (dst -> 123 fixed-capacity buckets), block counting sort
    scatterk<<<NB_EQ, 512, 0, stream>>>((const iv4*)src, (const iv4*)dst,
                                        (const fv4*)w, sci + 832, pairs, wp);

    // three aggregation rounds; packed u64 atomics in rounds 1/2
    agg1k<<<NAGG, 512, 0, stream>>>(pairs, sci + 832, x, slabU);
    mergeN1<<<NB_N, 256, 0, stream>>>(slabU, x, UN2, ENC);
    agg2k<<<NAGG, 512, 0, stream>>>(pairs, sci + 832, ENC, slabU);
    mergeN2<<<NB_N, 256, 0, stream>>>(slabU, SU, SN);
    agg3k<<<NAGG, 512, 0, stream>>>(pairs, sci + 832, SU, slab);
    m3mom<<<NB_N, 256, 0, stream>>>(slab, UN2, SU, SN, SSU, dm);

    // closed-form logit matrix (1 block, wave-parallel)
    constk<<<1, 64, 0, stream>>>(W1a, b1a, W1b, b1b, g1, be1,
                                 W2a, b2a, W2b, b2b, g2, be2,
                                 W3a, b3a, W3b, b3b, g3, be3,
                                 Wf, bfb, dm, sc + 160);

    // softmax -> modularity -> q (tiny separate kernel; fences are poison)
    finalk<<<NB_N, 256, 0, stream>>>(UN2, SU, SN, SSU, sc + 160, (float4*)sout, sbf);
    modk<<<NAGG, 512, 0, stream>>>(pairs, wp, sci + 832, (const u64*)sbf, sc);
    qk<<<1, 64, 0, stream>>>(sc, sout);
}